// Round 7
// baseline (1065.946 us; speedup 1.0000x reference)
//
#include <hip/hip_runtime.h>
#include <hip/hip_bf16.h>

// ---------------------------------------------------------------------------
// CapsuleNet forward. Round 7: routing rebuilt on transposed u_hat.
//  - uhat_t writes uT[b][jd 160][i 1152] bf16 (lane->i, coalesced), using
//    one-time W transpose Wr[jd*8+k][i] and caps^T staged in LDS.
//  - route_fused: ONE kernel, 3 iterations inside; b_ij in registers,
//    c in LDS (stride 11), v in LDS; phase A shuffle-free, phase B one
//    wave-reduce per jd. No bbuf.
//
// Workspace layout (bytes), total ~116.1 MB:
//   h_t   @ 0           : 52,428,800   (conv phase)
//   A2    @ 52,428,800  : 10,616,832  -> 63,045,632
//   caps4 @ 63,045,632  : 37,748,736  -> 100,794,368
//   uT    @ 0           : 94,371,840   (overlays ht/A2/caps4 — dead by uhat_t)
//   caps  @ 100,794,368 : 9,437,184   -> 110,231,552
//   Wr    @ 110,231,552 : 5,898,240   -> 116,129,792
// ---------------------------------------------------------------------------

typedef __attribute__((ext_vector_type(8))) short short8;
typedef __attribute__((ext_vector_type(4))) float float4v;

__device__ inline float bfu(ushort v){ return __uint_as_float((unsigned)v << 16); }

// conv1: x[256,1,28,28] * w[256,1,9,9] -> h_t[b][pos 400][c 256] bf16
__global__ __launch_bounds__(640) void conv1_kernel(const float* __restrict__ x,
    const float* __restrict__ w, const float* __restrict__ bias,
    __hip_bfloat16* __restrict__ ht){
  __shared__ float img[784];
  __shared__ float wsv[32 * 81];
  __shared__ ushort tile[400 * 33];
  int b = blockIdx.x;
  int og = blockIdx.y;
  int t = threadIdx.x;
  const float* xb = x + (size_t)b * 784;
  for (int idx = t; idx < 784; idx += 640) img[idx] = xb[idx];
  for (int idx = t; idx < 2592; idx += 640) wsv[idx] = w[(size_t)og * 2592 + idx];
  __syncthreads();
  int o_l = t / 20;
  int y   = t - o_l * 20;
  float acc[20];
  #pragma unroll
  for (int i = 0; i < 20; i++) acc[i] = 0.f;
  #pragma unroll
  for (int r = 0; r < 9; r++){
    float row[28];
    const float4* rp = (const float4*)&img[(y + r) * 28];
    #pragma unroll
    for (int q = 0; q < 7; q++){
      float4 v4 = rp[q];
      row[4*q+0]=v4.x; row[4*q+1]=v4.y; row[4*q+2]=v4.z; row[4*q+3]=v4.w;
    }
    #pragma unroll
    for (int s = 0; s < 9; s++){
      float wv = wsv[o_l * 81 + r * 9 + s];
      #pragma unroll
      for (int xx = 0; xx < 20; xx++)
        acc[xx] = fmaf(wv, row[xx + s], acc[xx]);
    }
  }
  float bv = bias[og * 32 + o_l];
  #pragma unroll
  for (int xx = 0; xx < 20; xx++){
    __hip_bfloat16 hv = __float2bfloat16(acc[xx] + bv);
    tile[(y * 20 + xx) * 33 + o_l] = *(ushort*)&hv;
  }
  __syncthreads();
  __hip_bfloat16* hb = ht + (size_t)b * 102400 + og * 32;
  for (int idx = t; idx < 6400; idx += 640){
    int pos = idx >> 4, op = idx & 15;
    unsigned v = (unsigned)tile[pos * 33 + op * 2]
               | ((unsigned)tile[pos * 33 + op * 2 + 1] << 16);
    *(unsigned*)(hb + (size_t)pos * 256 + op * 2) = v;
  }
}

// repack conv2 weights (wave-tiled, same as R6)
__global__ __launch_bounds__(256) void arepack_kernel(const float* __restrict__ w2,
    ushort* __restrict__ A2s){
  __shared__ float wbuf[64 * 81];
  int o = blockIdx.x;
  int t = threadIdx.x;
  int ow = o >> 6, fo = (o >> 4) & 3, l15 = o & 15;
  size_t obase8 = (size_t)ow * 165888 + (size_t)fo * 64 + (size_t)l15 * 4;
  for (int c0 = 0; c0 < 256; c0 += 64){
    __syncthreads();
    for (int idx = t; idx < 5184; idx += 256)
      wbuf[idx] = w2[(size_t)o * 20736 + (size_t)c0 * 81 + idx];
    __syncthreads();
    for (int idx = t; idx < 2592; idx += 256){
      int rs = idx >> 5;
      int cp = (idx & 31) * 2;
      int cg = c0 + cp;
      int ct = cg >> 5, quad = (cg >> 3) & 3, e = cg & 7;
      __hip_bfloat16 b0 = __float2bfloat16(wbuf[cp * 81 + rs]);
      __hip_bfloat16 b1 = __float2bfloat16(wbuf[(cp + 1) * 81 + rs]);
      unsigned pack = (unsigned)*(ushort*)&b0 | ((unsigned)*(ushort*)&b1 << 16);
      size_t si = (obase8 + (size_t)ct * 256 + (size_t)rs * 2048 + quad) * 8 + e;
      *(unsigned*)(A2s + si) = pack;
    }
  }
}

// W [1152][1280] -> Wr [1280][1152] (jdk-major) via LDS tile transpose
__global__ __launch_bounds__(256) void wrepack_kernel(const float* __restrict__ W,
    float* __restrict__ Wr){
  __shared__ float tile[64][65];
  int r0 = blockIdx.x * 64;  // i
  int c0 = blockIdx.y * 64;  // jdk
  int t = threadIdx.x; int lx = t & 63, ly = t >> 6;
  for (int rr = ly; rr < 64; rr += 4)
    tile[rr][lx] = W[(size_t)(r0 + rr) * 1280 + c0 + lx];
  __syncthreads();
  for (int rr = ly; rr < 64; rr += 4)
    Wr[(size_t)(c0 + rr) * 1152 + r0 + lx] = tile[lx][rr];
}

// conv2 implicit GEMM, 2 images/block (same as R6)
__global__ __launch_bounds__(256, 2) void conv2_mfma_kernel(
    const __hip_bfloat16* __restrict__ ht, const short8* __restrict__ A2,
    float* __restrict__ caps4){
  __shared__ ushort img[2][400 * 40];
  int bx  = blockIdx.x;
  int xcd = bx & 7;
  int kq  = xcd >> 1;
  int p   = ((bx >> 3) << 1) | (xcd & 1);
  int b0  = p * 2;
  int t = threadIdx.x;
  int lane = t & 63;
  int wid  = t >> 6;
  int l15  = lane & 15;
  int quad = lane >> 4;

  int bn[3], slc[3];
  #pragma unroll
  for (int fn = 0; fn < 3; fn++){
    int n = fn * 16 + l15;
    int y = n / 6, xx = n - y * 6;
    if (n >= 36){ y = 0; xx = 0; }
    bn[fn]  = 40 * y + 2 * xx;
    slc[fn] = (quad + 4 * y) % 5;
  }
  const short8* i0p = (const short8*)&img[0][0];
  const short8* i1p = (const short8*)&img[1][0];

  float4v acc[4][6];
  #pragma unroll
  for (int fo = 0; fo < 4; fo++)
    #pragma unroll
    for (int fn = 0; fn < 6; fn++)
      acc[fo][fn] = (float4v){0.f, 0.f, 0.f, 0.f};

  for (int ci = 0; ci < 2; ci++){
    int ct = kq * 2 + ci;
    __syncthreads();
    #pragma unroll
    for (int im = 0; im < 2; im++){
      const __hip_bfloat16* hb = ht + (size_t)(b0 + im) * 102400;
      for (int idx = t; idx < 1600; idx += 256){
        int pp = idx >> 2, q = idx & 3;
        int sl = (q + 2 * (pp / 20)) % 5;
        uint4 v = *(const uint4*)(hb + (size_t)pp * 256 + ct * 32 + q * 8);
        *(uint4*)&img[im][pp * 40 + sl * 8] = v;
      }
    }
    __syncthreads();

    const short8* ap = A2 + ((size_t)wid * 648 + ct) * 256 + l15 * 4 + quad;

    short8 aF[2][4], bF[2][6];
    #pragma unroll
    for (int fo = 0; fo < 4; fo++) aF[0][fo] = ap[fo * 64];
    #pragma unroll
    for (int fn = 0; fn < 6; fn++){
      int f3 = (fn < 3) ? fn : fn - 3;
      const short8* ib = (fn < 3) ? i0p : i1p;
      bF[0][fn] = ib[bn[f3] * 5 + slc[f3]];
    }

    int rn = 0, sn = 0, r2m = 0;
    #pragma unroll 2
    for (int rs = 0; rs < 81; rs++){
      int cur = rs & 1, nxt = cur ^ 1;
      sn++;
      if (sn == 9){ sn = 0; rn++; r2m += 2; if (r2m >= 5) r2m -= 5; }
      int nrs = (rs < 80) ? rs + 1 : 80;
      int roff = rn * 20 + sn;
      const short8* apn = ap + (size_t)nrs * 2048;
      #pragma unroll
      for (int fo = 0; fo < 4; fo++) aF[nxt][fo] = apn[fo * 64];
      #pragma unroll
      for (int fn = 0; fn < 6; fn++){
        int f3 = (fn < 3) ? fn : fn - 3;
        const short8* ib = (fn < 3) ? i0p : i1p;
        int sl = slc[f3] + r2m; if (sl >= 5) sl -= 5;
        bF[nxt][fn] = ib[(bn[f3] + roff) * 5 + sl];
      }
      #pragma unroll
      for (int fo = 0; fo < 4; fo++)
        #pragma unroll
        for (int fn = 0; fn < 6; fn++)
          acc[fo][fn] = __builtin_amdgcn_mfma_f32_16x16x32_bf16(aF[cur][fo], bF[cur][fn], acc[fo][fn], 0, 0, 0);
    }
  }

  #pragma unroll
  for (int fn = 0; fn < 6; fn++){
    int im = (fn < 3) ? 0 : 1;
    int f3 = (fn < 3) ? fn : fn - 3;
    int pos = f3 * 16 + l15;
    if (pos < 36){
      float* cb = caps4 + ((size_t)kq * 256 + b0 + im) * 9216;
      #pragma unroll
      for (int fo = 0; fo < 4; fo++){
        int ob = wid * 64 + fo * 16 + quad * 4;
        #pragma unroll
        for (int rr = 0; rr < 4; rr++)
          cb[(size_t)(ob + rr) * 36 + pos] = acc[fo][fn][rr];
      }
    }
  }
}

// sum 4 kq-partials + bias, squash -> caps [b][i][8] fp32
__global__ __launch_bounds__(256) void squash4_kernel(const float* __restrict__ caps4,
    const float* __restrict__ bias, float* __restrict__ caps){
  size_t cid = (size_t)blockIdx.x * 256 + threadIdx.x;
  size_t base = cid * 8;
  const size_t STR = 2359296;
  float4 a0 = *(const float4*)(caps4 + base);
  float4 a1 = *(const float4*)(caps4 + base + 4);
  #pragma unroll
  for (int k = 1; k < 4; k++){
    float4 q0 = *(const float4*)(caps4 + k * STR + base);
    float4 q1 = *(const float4*)(caps4 + k * STR + base + 4);
    a0.x+=q0.x; a0.y+=q0.y; a0.z+=q0.z; a0.w+=q0.w;
    a1.x+=q1.x; a1.y+=q1.y; a1.z+=q1.z; a1.w+=q1.w;
  }
  int off = (int)(base % 9216);
  float v[8] = {a0.x,a0.y,a0.z,a0.w,a1.x,a1.y,a1.z,a1.w};
  #pragma unroll
  for (int e = 0; e < 8; e++) v[e] += bias[(off + e) / 36];
  float msq = 0.f;
  #pragma unroll
  for (int e = 0; e < 8; e++) msq += v[e]*v[e];
  float scale = sqrtf(msq) / (1.f + msq);
  float* cp = caps + base;
  #pragma unroll
  for (int e = 0; e < 8; e++) cp[e] = v[e]*scale;
}

// uT[b][jd][i] = sum_k Wr[jd*8+k][i] * caps[b][i][k]   (bf16 out)
// block 256 = 4 waves (wave -> 40 jd), lane -> i (64-tile), 8 b per block.
__global__ __launch_bounds__(256) void uhat_t_kernel(const float* __restrict__ caps,
    const float* __restrict__ Wr, ushort* __restrict__ uT){
  __shared__ float cl[8 * 8 * 64];   // [k][bb][il] = (k*8+bb)*64+il, 16 KB
  int i0 = blockIdx.x * 64;   // 18
  int b0 = blockIdx.y * 8;    // 32
  int t = threadIdx.x, lane = t & 63, w = t >> 6;
  for (int f = t; f < 1024; f += 256){
    int base = f * 4; int bb = base >> 9; int r = base & 511;
    int il = r >> 3; int k = r & 7;
    float4 v = *(const float4*)(caps + ((size_t)(b0+bb)*1152 + i0 + il)*8 + k);
    cl[((k+0)*8+bb)*64+il] = v.x;
    cl[((k+1)*8+bb)*64+il] = v.y;
    cl[((k+2)*8+bb)*64+il] = v.z;
    cl[((k+3)*8+bb)*64+il] = v.w;
  }
  __syncthreads();
  for (int jj = 0; jj < 40; jj++){
    int jd = w * 40 + jj;
    float wk[8];
    #pragma unroll
    for (int k = 0; k < 8; k++)
      wk[k] = Wr[((size_t)jd * 8 + k) * 1152 + i0 + lane];
    #pragma unroll
    for (int bb = 0; bb < 8; bb++){
      float acc = 0.f;
      #pragma unroll
      for (int k = 0; k < 8; k++) acc = fmaf(wk[k], cl[(k*8+bb)*64+lane], acc);
      __hip_bfloat16 hv = __float2bfloat16(acc);
      uT[((size_t)(b0+bb)*160 + jd)*1152 + i0 + lane] = *(ushort*)&hv;
    }
  }
}

// fused routing: 3 iterations in one launch. block 576 (9 waves), grid 256.
// Phase A: lane->i (wave stripe of 128 i), dots/softmax thread-local, c->LDS.
// Phase B: wave->jd (jd = w, w+9, ...), lanes->i, one 6-shfl reduce per jd.
__global__ __launch_bounds__(576) void route_fused_kernel(
    const ushort* __restrict__ uT, const float* __restrict__ dcb,
    float* __restrict__ out){
  __shared__ float clds[1152 * 11];   // c[i][j], stride 11 (conflict-free)
  __shared__ float s_lds[160];
  __shared__ float vs[160];
  int b = blockIdx.x;
  int t = threadIdx.x;
  int lane = t & 63, w = t >> 6;      // 9 waves
  const ushort* ubT = uT + (size_t)b * 184320;
  float breg[20];
  #pragma unroll
  for (int q = 0; q < 20; q++) breg[q] = 0.f;

  for (int iter = 0; iter < 3; iter++){
    if (iter){
      // ---- phase A: dots -> b update -> softmax -> c
      #pragma unroll
      for (int ih = 0; ih < 2; ih++){
        int i = w * 128 + ih * 64 + lane;
        const ushort* up = ubT + i;
        float* bp = &breg[ih * 10];
        #pragma unroll
        for (int j = 0; j < 10; j++){
          float dj = 0.f;
          #pragma unroll
          for (int d = 0; d < 16; d++){
            int jd = j * 16 + d;
            dj = fmaf(bfu(up[(size_t)jd * 1152]), vs[jd], dj);
          }
          bp[j] += dj;
        }
        float m = bp[0];
        #pragma unroll
        for (int j = 1; j < 10; j++) m = fmaxf(m, bp[j]);
        float e[10], se = 0.f;
        #pragma unroll
        for (int j = 0; j < 10; j++){ e[j] = __expf(bp[j] - m); se += e[j]; }
        float inv = 1.f / se;
        #pragma unroll
        for (int j = 0; j < 10; j++) clds[i * 11 + j] = e[j] * inv;
      }
      __syncthreads();
    }
    // ---- phase B: s[jd] = sum_i c[i][j] * u[i][jd]
    for (int jd = w; jd < 160; jd += 9){
      const ushort* urow = ubT + (size_t)jd * 1152;
      float sacc = 0.f;
      if (iter == 0){
        #pragma unroll
        for (int st = 0; st < 18; st++)
          sacc += bfu(urow[st * 64 + lane]);
      } else {
        int jj = jd >> 4;
        #pragma unroll
        for (int st = 0; st < 18; st++){
          int i = st * 64 + lane;
          sacc = fmaf(bfu(urow[i]), clds[i * 11 + jj], sacc);
        }
      }
      sacc += __shfl_xor(sacc, 32);
      sacc += __shfl_xor(sacc, 16);
      sacc += __shfl_xor(sacc, 8);
      sacc += __shfl_xor(sacc, 4);
      sacc += __shfl_xor(sacc, 2);
      sacc += __shfl_xor(sacc, 1);
      if (lane == 0) s_lds[jd] = (iter == 0) ? sacc * 0.1f : sacc;
    }
    __syncthreads();
    if (t < 160){
      float sv = s_lds[t] + dcb[t];
      float msq = sv * sv;
      msq += __shfl_xor(msq, 1, 16);
      msq += __shfl_xor(msq, 2, 16);
      msq += __shfl_xor(msq, 4, 16);
      msq += __shfl_xor(msq, 8, 16);
      float scale = sqrtf(msq) / (1.f + msq);
      if (iter == 2) out[b * 160 + t] = sv * scale;
      else vs[t] = sv * scale;
    }
    __syncthreads();
  }
}

extern "C" void kernel_launch(void* const* d_in, const int* in_sizes, int n_in,
                              void* d_out, int out_size, void* d_ws, size_t ws_size,
                              hipStream_t stream){
  (void)in_sizes; (void)n_in; (void)out_size; (void)ws_size;
  const float* x   = (const float*)d_in[0];
  const float* w1  = (const float*)d_in[1];
  const float* b1  = (const float*)d_in[2];
  const float* w2  = (const float*)d_in[3];
  const float* b2  = (const float*)d_in[4];
  const float* W   = (const float*)d_in[5];
  const float* dcb = (const float*)d_in[6];
  float* out = (float*)d_out;

  char* ws = (char*)d_ws;
  __hip_bfloat16* ht = (__hip_bfloat16*)(ws);
  ushort* A2s  = (ushort*)(ws + 52428800);
  float* caps4 = (float*)(ws + 63045632);
  ushort* uT   = (ushort*)(ws);                  // overlays ht/A2/caps4 (dead)
  float* caps  = (float*)(ws + 100794368);
  float* Wr    = (float*)(ws + 110231552);

  conv1_kernel<<<dim3(256, 8), 640, 0, stream>>>(x, w1, b1, ht);
  arepack_kernel<<<256, 256, 0, stream>>>(w2, A2s);
  wrepack_kernel<<<dim3(18, 20), 256, 0, stream>>>(W, Wr);
  conv2_mfma_kernel<<<512, 256, 0, stream>>>(ht, (const short8*)A2s, caps4);
  squash4_kernel<<<1152, 256, 0, stream>>>(caps4, b2, caps);
  uhat_t_kernel<<<dim3(18, 32), 256, 0, stream>>>(caps, Wr, uT);
  route_fused_kernel<<<256, 576, 0, stream>>>(uT, dcb, out);
}

// Round 8
// 480.873 us; speedup vs baseline: 2.2167x; 2.2167x over previous
//
#include <hip/hip_runtime.h>
#include <hip/hip_bf16.h>

// ---------------------------------------------------------------------------
// CapsuleNet forward. Round 8: routing parallelism fix.
//  - routeAB: grid (3 i-chunks x 256 images), 384 thr (18 waves/CU).
//    Phase A thread-local dots/softmax (no shuffles); phase B wave->jd with
//    L2-hot re-read of the chunk's u slice; partials to spart.
//  - vsq: sums 3 partials + bias, squash -> v (or final out).
//  - uhat_t: 16 images/block, Wr in bf16 (47 MB traffic, was 188).
//
// Workspace (bytes), total ~125.6 MB:
//   ht    @ 0           : 52,428,800  (conv phase)
//   A2    @ 52,428,800  : 10,616,832 -> 63,045,632
//   caps4 @ 63,045,632  : 37,748,736 -> 100,794,368
//   uT    @ 0           : 94,371,840  (overlays ht/A2/caps4)
//   caps  @ 100,794,368 : 9,437,184  -> 110,231,552
//   Wrb   @ 110,231,552 : 2,949,120  -> 113,180,672
//   bbuf  @ 113,180,672 : 11,796,480 -> 124,977,152
//   spart @ 124,977,152 : 491,520    -> 125,468,672
//   vbuf  @ 125,468,672 : 163,840    -> 125,632,512
// ---------------------------------------------------------------------------

typedef __attribute__((ext_vector_type(8))) short short8;
typedef __attribute__((ext_vector_type(4))) float float4v;

__device__ inline float bfu(ushort v){ return __uint_as_float((unsigned)v << 16); }

// conv1: x[256,1,28,28] * w[256,1,9,9] -> h_t[b][pos 400][c 256] bf16
__global__ __launch_bounds__(640) void conv1_kernel(const float* __restrict__ x,
    const float* __restrict__ w, const float* __restrict__ bias,
    __hip_bfloat16* __restrict__ ht){
  __shared__ float img[784];
  __shared__ float wsv[32 * 81];
  __shared__ ushort tile[400 * 33];
  int b = blockIdx.x;
  int og = blockIdx.y;
  int t = threadIdx.x;
  const float* xb = x + (size_t)b * 784;
  for (int idx = t; idx < 784; idx += 640) img[idx] = xb[idx];
  for (int idx = t; idx < 2592; idx += 640) wsv[idx] = w[(size_t)og * 2592 + idx];
  __syncthreads();
  int o_l = t / 20;
  int y   = t - o_l * 20;
  float acc[20];
  #pragma unroll
  for (int i = 0; i < 20; i++) acc[i] = 0.f;
  #pragma unroll
  for (int r = 0; r < 9; r++){
    float row[28];
    const float4* rp = (const float4*)&img[(y + r) * 28];
    #pragma unroll
    for (int q = 0; q < 7; q++){
      float4 v4 = rp[q];
      row[4*q+0]=v4.x; row[4*q+1]=v4.y; row[4*q+2]=v4.z; row[4*q+3]=v4.w;
    }
    #pragma unroll
    for (int s = 0; s < 9; s++){
      float wv = wsv[o_l * 81 + r * 9 + s];
      #pragma unroll
      for (int xx = 0; xx < 20; xx++)
        acc[xx] = fmaf(wv, row[xx + s], acc[xx]);
    }
  }
  float bv = bias[og * 32 + o_l];
  #pragma unroll
  for (int xx = 0; xx < 20; xx++){
    __hip_bfloat16 hv = __float2bfloat16(acc[xx] + bv);
    tile[(y * 20 + xx) * 33 + o_l] = *(ushort*)&hv;
  }
  __syncthreads();
  __hip_bfloat16* hb = ht + (size_t)b * 102400 + og * 32;
  for (int idx = t; idx < 6400; idx += 640){
    int pos = idx >> 4, op = idx & 15;
    unsigned v = (unsigned)tile[pos * 33 + op * 2]
               | ((unsigned)tile[pos * 33 + op * 2 + 1] << 16);
    *(unsigned*)(hb + (size_t)pos * 256 + op * 2) = v;
  }
}

// repack conv2 weights (wave-tiled)
__global__ __launch_bounds__(256) void arepack_kernel(const float* __restrict__ w2,
    ushort* __restrict__ A2s){
  __shared__ float wbuf[64 * 81];
  int o = blockIdx.x;
  int t = threadIdx.x;
  int ow = o >> 6, fo = (o >> 4) & 3, l15 = o & 15;
  size_t obase8 = (size_t)ow * 165888 + (size_t)fo * 64 + (size_t)l15 * 4;
  for (int c0 = 0; c0 < 256; c0 += 64){
    __syncthreads();
    for (int idx = t; idx < 5184; idx += 256)
      wbuf[idx] = w2[(size_t)o * 20736 + (size_t)c0 * 81 + idx];
    __syncthreads();
    for (int idx = t; idx < 2592; idx += 256){
      int rs = idx >> 5;
      int cp = (idx & 31) * 2;
      int cg = c0 + cp;
      int ct = cg >> 5, quad = (cg >> 3) & 3, e = cg & 7;
      __hip_bfloat16 b0 = __float2bfloat16(wbuf[cp * 81 + rs]);
      __hip_bfloat16 b1 = __float2bfloat16(wbuf[(cp + 1) * 81 + rs]);
      unsigned pack = (unsigned)*(ushort*)&b0 | ((unsigned)*(ushort*)&b1 << 16);
      size_t si = (obase8 + (size_t)ct * 256 + (size_t)rs * 2048 + quad) * 8 + e;
      *(unsigned*)(A2s + si) = pack;
    }
  }
}

// W [1152][1280] f32 -> Wrb [1280][1152] bf16 (transposed)
__global__ __launch_bounds__(256) void wrepack_kernel(const float* __restrict__ W,
    ushort* __restrict__ Wrb){
  __shared__ float tile[64][65];
  int r0 = blockIdx.x * 64;  // i
  int c0 = blockIdx.y * 64;  // jdk
  int t = threadIdx.x; int lx = t & 63, ly = t >> 6;
  for (int rr = ly; rr < 64; rr += 4)
    tile[rr][lx] = W[(size_t)(r0 + rr) * 1280 + c0 + lx];
  __syncthreads();
  for (int rr = ly; rr < 64; rr += 4){
    __hip_bfloat16 hv = __float2bfloat16(tile[lx][rr]);
    Wrb[(size_t)(c0 + rr) * 1152 + r0 + lx] = *(ushort*)&hv;
  }
}

// conv2 implicit GEMM, 2 images/block (R6-verified)
__global__ __launch_bounds__(256, 2) void conv2_mfma_kernel(
    const __hip_bfloat16* __restrict__ ht, const short8* __restrict__ A2,
    float* __restrict__ caps4){
  __shared__ ushort img[2][400 * 40];
  int bx  = blockIdx.x;
  int xcd = bx & 7;
  int kq  = xcd >> 1;
  int p   = ((bx >> 3) << 1) | (xcd & 1);
  int b0  = p * 2;
  int t = threadIdx.x;
  int lane = t & 63;
  int wid  = t >> 6;
  int l15  = lane & 15;
  int quad = lane >> 4;

  int bn[3], slc[3];
  #pragma unroll
  for (int fn = 0; fn < 3; fn++){
    int n = fn * 16 + l15;
    int y = n / 6, xx = n - y * 6;
    if (n >= 36){ y = 0; xx = 0; }
    bn[fn]  = 40 * y + 2 * xx;
    slc[fn] = (quad + 4 * y) % 5;
  }
  const short8* i0p = (const short8*)&img[0][0];
  const short8* i1p = (const short8*)&img[1][0];

  float4v acc[4][6];
  #pragma unroll
  for (int fo = 0; fo < 4; fo++)
    #pragma unroll
    for (int fn = 0; fn < 6; fn++)
      acc[fo][fn] = (float4v){0.f, 0.f, 0.f, 0.f};

  for (int ci = 0; ci < 2; ci++){
    int ct = kq * 2 + ci;
    __syncthreads();
    #pragma unroll
    for (int im = 0; im < 2; im++){
      const __hip_bfloat16* hb = ht + (size_t)(b0 + im) * 102400;
      for (int idx = t; idx < 1600; idx += 256){
        int pp = idx >> 2, q = idx & 3;
        int sl = (q + 2 * (pp / 20)) % 5;
        uint4 v = *(const uint4*)(hb + (size_t)pp * 256 + ct * 32 + q * 8);
        *(uint4*)&img[im][pp * 40 + sl * 8] = v;
      }
    }
    __syncthreads();

    const short8* ap = A2 + ((size_t)wid * 648 + ct) * 256 + l15 * 4 + quad;

    short8 aF[2][4], bF[2][6];
    #pragma unroll
    for (int fo = 0; fo < 4; fo++) aF[0][fo] = ap[fo * 64];
    #pragma unroll
    for (int fn = 0; fn < 6; fn++){
      int f3 = (fn < 3) ? fn : fn - 3;
      const short8* ib = (fn < 3) ? i0p : i1p;
      bF[0][fn] = ib[bn[f3] * 5 + slc[f3]];
    }

    int rn = 0, sn = 0, r2m = 0;
    #pragma unroll 2
    for (int rs = 0; rs < 81; rs++){
      int cur = rs & 1, nxt = cur ^ 1;
      sn++;
      if (sn == 9){ sn = 0; rn++; r2m += 2; if (r2m >= 5) r2m -= 5; }
      int nrs = (rs < 80) ? rs + 1 : 80;
      int roff = rn * 20 + sn;
      const short8* apn = ap + (size_t)nrs * 2048;
      #pragma unroll
      for (int fo = 0; fo < 4; fo++) aF[nxt][fo] = apn[fo * 64];
      #pragma unroll
      for (int fn = 0; fn < 6; fn++){
        int f3 = (fn < 3) ? fn : fn - 3;
        const short8* ib = (fn < 3) ? i0p : i1p;
        int sl = slc[f3] + r2m; if (sl >= 5) sl -= 5;
        bF[nxt][fn] = ib[(bn[f3] + roff) * 5 + sl];
      }
      #pragma unroll
      for (int fo = 0; fo < 4; fo++)
        #pragma unroll
        for (int fn = 0; fn < 6; fn++)
          acc[fo][fn] = __builtin_amdgcn_mfma_f32_16x16x32_bf16(aF[cur][fo], bF[cur][fn], acc[fo][fn], 0, 0, 0);
    }
  }

  #pragma unroll
  for (int fn = 0; fn < 6; fn++){
    int im = (fn < 3) ? 0 : 1;
    int f3 = (fn < 3) ? fn : fn - 3;
    int pos = f3 * 16 + l15;
    if (pos < 36){
      float* cb = caps4 + ((size_t)kq * 256 + b0 + im) * 9216;
      #pragma unroll
      for (int fo = 0; fo < 4; fo++){
        int ob = wid * 64 + fo * 16 + quad * 4;
        #pragma unroll
        for (int rr = 0; rr < 4; rr++)
          cb[(size_t)(ob + rr) * 36 + pos] = acc[fo][fn][rr];
      }
    }
  }
}

// sum 4 kq-partials + bias, squash -> caps [b][i][8] fp32
__global__ __launch_bounds__(256) void squash4_kernel(const float* __restrict__ caps4,
    const float* __restrict__ bias, float* __restrict__ caps){
  size_t cid = (size_t)blockIdx.x * 256 + threadIdx.x;
  size_t base = cid * 8;
  const size_t STR = 2359296;
  float4 a0 = *(const float4*)(caps4 + base);
  float4 a1 = *(const float4*)(caps4 + base + 4);
  #pragma unroll
  for (int k = 1; k < 4; k++){
    float4 q0 = *(const float4*)(caps4 + k * STR + base);
    float4 q1 = *(const float4*)(caps4 + k * STR + base + 4);
    a0.x+=q0.x; a0.y+=q0.y; a0.z+=q0.z; a0.w+=q0.w;
    a1.x+=q1.x; a1.y+=q1.y; a1.z+=q1.z; a1.w+=q1.w;
  }
  int off = (int)(base % 9216);
  float v[8] = {a0.x,a0.y,a0.z,a0.w,a1.x,a1.y,a1.z,a1.w};
  #pragma unroll
  for (int e = 0; e < 8; e++) v[e] += bias[(off + e) / 36];
  float msq = 0.f;
  #pragma unroll
  for (int e = 0; e < 8; e++) msq += v[e]*v[e];
  float scale = sqrtf(msq) / (1.f + msq);
  float* cp = caps + base;
  #pragma unroll
  for (int e = 0; e < 8; e++) cp[e] = v[e]*scale;
}

// uT[b][jd][i] = sum_k Wrb[jd*8+k][i] * caps[b][i][k]  (bf16 out)
// grid (18 i-chunks, 16 b-groups); block 256 = 4 waves (wave -> 40 jd).
__global__ __launch_bounds__(256) void uhat_t_kernel(const float* __restrict__ caps,
    const ushort* __restrict__ Wrb, ushort* __restrict__ uT){
  __shared__ float cl[8 * 16 * 64];   // [k][bb][il], 32 KB
  int i0 = blockIdx.x * 64;
  int b0 = blockIdx.y * 16;
  int t = threadIdx.x, lane = t & 63, w = t >> 6;
  for (int f = t; f < 2048; f += 256){
    int base = f * 4; int bb = base >> 9; int r = base & 511;
    int il = r >> 3; int k = r & 7;
    float4 v = *(const float4*)(caps + ((size_t)(b0+bb)*1152 + i0 + il)*8 + k);
    cl[((k+0)*16+bb)*64+il] = v.x;
    cl[((k+1)*16+bb)*64+il] = v.y;
    cl[((k+2)*16+bb)*64+il] = v.z;
    cl[((k+3)*16+bb)*64+il] = v.w;
  }
  __syncthreads();
  for (int jj = 0; jj < 40; jj++){
    int jd = w * 40 + jj;
    float wk[8];
    #pragma unroll
    for (int k = 0; k < 8; k++)
      wk[k] = bfu(Wrb[((size_t)jd * 8 + k) * 1152 + i0 + lane]);
    #pragma unroll
    for (int bb = 0; bb < 16; bb++){
      float acc = 0.f;
      #pragma unroll
      for (int k = 0; k < 8; k++) acc = fmaf(wk[k], cl[(k*16+bb)*64+lane], acc);
      __hip_bfloat16 hv = __float2bfloat16(acc);
      uT[((size_t)(b0+bb)*160 + jd)*1152 + i0 + lane] = *(ushort*)&hv;
    }
  }
}

// routing iteration: phase A (dots -> b -> softmax -> c, thread->i) +
// phase B (wave->jd, lanes->i, L2-hot re-read). grid (3 chunks, 256 b).
// mode 0: c uniform 0.1 (phase B only); 1: b=d (write); 2: b+=d (read).
__global__ __launch_bounds__(384) void routeAB_kernel(
    const ushort* __restrict__ uT, const float* __restrict__ vin,
    float* __restrict__ bbuf, float* __restrict__ spart, int mode){
  __shared__ float c_l[384 * 11];
  __shared__ float vs[160];
  int ic = blockIdx.x;   // 0..2
  int b  = blockIdx.y;   // 0..255
  int t = threadIdx.x;
  int lane = t & 63, w = t >> 6;   // 6 waves
  const ushort* ub = uT + (size_t)b * 184320 + ic * 384;

  if (mode){
    if (t < 160) vs[t] = vin[b * 160 + t];
    __syncthreads();
    const ushort* up = ub + t;
    float d[10];
    #pragma unroll
    for (int j = 0; j < 10; j++){
      float dj = 0.f;
      #pragma unroll
      for (int dd = 0; dd < 16; dd++){
        int jd = j * 16 + dd;
        dj = fmaf(bfu(up[(size_t)jd * 1152]), vs[jd], dj);
      }
      d[j] = dj;
    }
    float* bp = bbuf + ((size_t)b * 1152 + ic * 384 + t) * 10;
    if (mode == 2){
      #pragma unroll
      for (int j = 0; j < 10; j++) d[j] += bp[j];
    } else {
      #pragma unroll
      for (int j = 0; j < 10; j++) bp[j] = d[j];
    }
    float m = d[0];
    #pragma unroll
    for (int j = 1; j < 10; j++) m = fmaxf(m, d[j]);
    float se = 0.f;
    #pragma unroll
    for (int j = 0; j < 10; j++){ d[j] = __expf(d[j] - m); se += d[j]; }
    float inv = 1.f / se;
    #pragma unroll
    for (int j = 0; j < 10; j++) c_l[t * 11 + j] = d[j] * inv;
  }
  __syncthreads();

  for (int jd = w; jd < 160; jd += 6){
    const ushort* urow = ub + (size_t)jd * 1152;
    float sacc = 0.f;
    if (mode){
      int jj = jd >> 4;
      #pragma unroll
      for (int st = 0; st < 6; st++){
        int i_l = st * 64 + lane;
        sacc = fmaf(bfu(urow[i_l]), c_l[i_l * 11 + jj], sacc);
      }
    } else {
      #pragma unroll
      for (int st = 0; st < 6; st++) sacc += bfu(urow[st * 64 + lane]);
    }
    sacc += __shfl_xor(sacc, 32);
    sacc += __shfl_xor(sacc, 16);
    sacc += __shfl_xor(sacc, 8);
    sacc += __shfl_xor(sacc, 4);
    sacc += __shfl_xor(sacc, 2);
    sacc += __shfl_xor(sacc, 1);
    if (lane == 0) spart[((size_t)ic * 256 + b) * 160 + jd] = mode ? sacc : sacc * 0.1f;
  }
}

// sum 3 chunk partials + bias, squash over 16-groups -> v (or final out)
__global__ __launch_bounds__(160) void vsq_kernel(const float* __restrict__ spart,
    const float* __restrict__ dcb, float* __restrict__ vout){
  int b = blockIdx.x;
  int t = threadIdx.x;   // 0..159
  float s = dcb[t];
  #pragma unroll
  for (int ic = 0; ic < 3; ic++) s += spart[((size_t)ic * 256 + b) * 160 + t];
  float msq = s * s;
  msq += __shfl_xor(msq, 1, 16);
  msq += __shfl_xor(msq, 2, 16);
  msq += __shfl_xor(msq, 4, 16);
  msq += __shfl_xor(msq, 8, 16);
  float scale = sqrtf(msq) / (1.f + msq);
  vout[b * 160 + t] = s * scale;
}

extern "C" void kernel_launch(void* const* d_in, const int* in_sizes, int n_in,
                              void* d_out, int out_size, void* d_ws, size_t ws_size,
                              hipStream_t stream){
  (void)in_sizes; (void)n_in; (void)out_size; (void)ws_size;
  const float* x   = (const float*)d_in[0];
  const float* w1  = (const float*)d_in[1];
  const float* b1  = (const float*)d_in[2];
  const float* w2  = (const float*)d_in[3];
  const float* b2  = (const float*)d_in[4];
  const float* W   = (const float*)d_in[5];
  const float* dcb = (const float*)d_in[6];
  float* out = (float*)d_out;

  char* ws = (char*)d_ws;
  __hip_bfloat16* ht = (__hip_bfloat16*)(ws);
  ushort* A2s  = (ushort*)(ws + 52428800);
  float* caps4 = (float*)(ws + 63045632);
  ushort* uT   = (ushort*)(ws);                  // overlays ht/A2/caps4 (dead)
  float* caps  = (float*)(ws + 100794368);
  ushort* Wrb  = (ushort*)(ws + 110231552);
  float* bbuf  = (float*)(ws + 113180672);
  float* spart = (float*)(ws + 124977152);
  float* vbuf  = (float*)(ws + 125468672);

  conv1_kernel<<<dim3(256, 8), 640, 0, stream>>>(x, w1, b1, ht);
  arepack_kernel<<<256, 256, 0, stream>>>(w2, A2s);
  wrepack_kernel<<<dim3(18, 20), 256, 0, stream>>>(W, Wrb);
  conv2_mfma_kernel<<<512, 256, 0, stream>>>(ht, (const short8*)A2s, caps4);
  squash4_kernel<<<1152, 256, 0, stream>>>(caps4, b2, caps);
  uhat_t_kernel<<<dim3(18, 16), 256, 0, stream>>>(caps, Wrb, uT);
  routeAB_kernel<<<dim3(3, 256), 384, 0, stream>>>(uT, vbuf, bbuf, spart, 0);
  vsq_kernel<<<256, 160, 0, stream>>>(spart, dcb, vbuf);
  routeAB_kernel<<<dim3(3, 256), 384, 0, stream>>>(uT, vbuf, bbuf, spart, 1);
  vsq_kernel<<<256, 160, 0, stream>>>(spart, dcb, vbuf);
  routeAB_kernel<<<dim3(3, 256), 384, 0, stream>>>(uT, vbuf, bbuf, spart, 2);
  vsq_kernel<<<256, 160, 0, stream>>>(spart, dcb, out);
}

// Round 10
// 392.710 us; speedup vs baseline: 2.7143x; 1.2245x over previous
//
#include <hip/hip_runtime.h>
#include <hip/hip_bf16.h>

// ---------------------------------------------------------------------------
// CapsuleNet forward. Round 10: R9 with uhat_t's 3D grid flattened to 2D
// (dim3(18,64); b0=(by>>2)*16, jd0=(by&3)*40). R9's post-timing divergence is
// consistent with the gridDim.z=4 launch not surviving graph replay (uT rows
// jd>=40 left at ws-poison in the timed path only). No other changes.
//
// Workspace (bytes), total ~125.6 MB:
//   ht    @ 0           : 52,428,800  (conv phase)
//   A2    @ 52,428,800  : 10,616,832 -> 63,045,632
//   caps4 @ 63,045,632  : 37,748,736 -> 100,794,368
//   uT    @ 0           : 94,371,840  (overlays ht/A2/caps4)
//   caps  @ 100,794,368 : 9,437,184  -> 110,231,552
//   Wrb   @ 110,231,552 : 2,949,120  -> 113,180,672
//   bbuf  @ 113,180,672 : 11,796,480 -> 124,977,152
//   spart @ 124,977,152 : 491,520    -> 125,468,672
//   vbuf  @ 125,468,672 : 163,840    -> 125,632,512
// ---------------------------------------------------------------------------

typedef __attribute__((ext_vector_type(8))) short short8;
typedef __attribute__((ext_vector_type(4))) float float4v;

__device__ inline float bfu(ushort v){ return __uint_as_float((unsigned)v << 16); }

// conv1: x[256,1,28,28] * w[256,1,9,9] -> h_t[b][pos 400][c 256] bf16
__global__ __launch_bounds__(640) void conv1_kernel(const float* __restrict__ x,
    const float* __restrict__ w, const float* __restrict__ bias,
    __hip_bfloat16* __restrict__ ht){
  __shared__ float img[784];
  __shared__ float wsv[32 * 81];
  __shared__ ushort tile[400 * 33];
  int b = blockIdx.x;
  int og = blockIdx.y;
  int t = threadIdx.x;
  const float* xb = x + (size_t)b * 784;
  for (int idx = t; idx < 784; idx += 640) img[idx] = xb[idx];
  for (int idx = t; idx < 2592; idx += 640) wsv[idx] = w[(size_t)og * 2592 + idx];
  __syncthreads();
  int o_l = t / 20;
  int y   = t - o_l * 20;
  float acc[20];
  #pragma unroll
  for (int i = 0; i < 20; i++) acc[i] = 0.f;
  #pragma unroll
  for (int r = 0; r < 9; r++){
    float row[28];
    const float4* rp = (const float4*)&img[(y + r) * 28];
    #pragma unroll
    for (int q = 0; q < 7; q++){
      float4 v4 = rp[q];
      row[4*q+0]=v4.x; row[4*q+1]=v4.y; row[4*q+2]=v4.z; row[4*q+3]=v4.w;
    }
    #pragma unroll
    for (int s = 0; s < 9; s++){
      float wv = wsv[o_l * 81 + r * 9 + s];
      #pragma unroll
      for (int xx = 0; xx < 20; xx++)
        acc[xx] = fmaf(wv, row[xx + s], acc[xx]);
    }
  }
  float bv = bias[og * 32 + o_l];
  #pragma unroll
  for (int xx = 0; xx < 20; xx++){
    __hip_bfloat16 hv = __float2bfloat16(acc[xx] + bv);
    tile[(y * 20 + xx) * 33 + o_l] = *(ushort*)&hv;
  }
  __syncthreads();
  __hip_bfloat16* hb = ht + (size_t)b * 102400 + og * 32;
  for (int idx = t; idx < 6400; idx += 640){
    int pos = idx >> 4, op = idx & 15;
    unsigned v = (unsigned)tile[pos * 33 + op * 2]
               | ((unsigned)tile[pos * 33 + op * 2 + 1] << 16);
    *(unsigned*)(hb + (size_t)pos * 256 + op * 2) = v;
  }
}

// repack conv2 weights (wave-tiled)
__global__ __launch_bounds__(256) void arepack_kernel(const float* __restrict__ w2,
    ushort* __restrict__ A2s){
  __shared__ float wbuf[64 * 81];
  int o = blockIdx.x;
  int t = threadIdx.x;
  int ow = o >> 6, fo = (o >> 4) & 3, l15 = o & 15;
  size_t obase8 = (size_t)ow * 165888 + (size_t)fo * 64 + (size_t)l15 * 4;
  for (int c0 = 0; c0 < 256; c0 += 64){
    __syncthreads();
    for (int idx = t; idx < 5184; idx += 256)
      wbuf[idx] = w2[(size_t)o * 20736 + (size_t)c0 * 81 + idx];
    __syncthreads();
    for (int idx = t; idx < 2592; idx += 256){
      int rs = idx >> 5;
      int cp = (idx & 31) * 2;
      int cg = c0 + cp;
      int ct = cg >> 5, quad = (cg >> 3) & 3, e = cg & 7;
      __hip_bfloat16 b0 = __float2bfloat16(wbuf[cp * 81 + rs]);
      __hip_bfloat16 b1 = __float2bfloat16(wbuf[(cp + 1) * 81 + rs]);
      unsigned pack = (unsigned)*(ushort*)&b0 | ((unsigned)*(ushort*)&b1 << 16);
      size_t si = (obase8 + (size_t)ct * 256 + (size_t)rs * 2048 + quad) * 8 + e;
      *(unsigned*)(A2s + si) = pack;
    }
  }
}

// W [1152][1280] f32 -> Wrb [1280][1152] bf16 (transposed)
__global__ __launch_bounds__(256) void wrepack_kernel(const float* __restrict__ W,
    ushort* __restrict__ Wrb){
  __shared__ float tile[64][65];
  int r0 = blockIdx.x * 64;  // i
  int c0 = blockIdx.y * 64;  // jdk
  int t = threadIdx.x; int lx = t & 63, ly = t >> 6;
  for (int rr = ly; rr < 64; rr += 4)
    tile[rr][lx] = W[(size_t)(r0 + rr) * 1280 + c0 + lx];
  __syncthreads();
  for (int rr = ly; rr < 64; rr += 4){
    __hip_bfloat16 hv = __float2bfloat16(tile[lx][rr]);
    Wrb[(size_t)(c0 + rr) * 1152 + r0 + lx] = *(ushort*)&hv;
  }
}

// conv2 implicit GEMM, 2 images/block (R6-verified)
__global__ __launch_bounds__(256, 2) void conv2_mfma_kernel(
    const __hip_bfloat16* __restrict__ ht, const short8* __restrict__ A2,
    float* __restrict__ caps4){
  __shared__ ushort img[2][400 * 40];
  int bx  = blockIdx.x;
  int xcd = bx & 7;
  int kq  = xcd >> 1;
  int p   = ((bx >> 3) << 1) | (xcd & 1);
  int b0  = p * 2;
  int t = threadIdx.x;
  int lane = t & 63;
  int wid  = t >> 6;
  int l15  = lane & 15;
  int quad = lane >> 4;

  int bn[3], slc[3];
  #pragma unroll
  for (int fn = 0; fn < 3; fn++){
    int n = fn * 16 + l15;
    int y = n / 6, xx = n - y * 6;
    if (n >= 36){ y = 0; xx = 0; }
    bn[fn]  = 40 * y + 2 * xx;
    slc[fn] = (quad + 4 * y) % 5;
  }
  const short8* i0p = (const short8*)&img[0][0];
  const short8* i1p = (const short8*)&img[1][0];

  float4v acc[4][6];
  #pragma unroll
  for (int fo = 0; fo < 4; fo++)
    #pragma unroll
    for (int fn = 0; fn < 6; fn++)
      acc[fo][fn] = (float4v){0.f, 0.f, 0.f, 0.f};

  for (int ci = 0; ci < 2; ci++){
    int ct = kq * 2 + ci;
    __syncthreads();
    #pragma unroll
    for (int im = 0; im < 2; im++){
      const __hip_bfloat16* hb = ht + (size_t)(b0 + im) * 102400;
      for (int idx = t; idx < 1600; idx += 256){
        int pp = idx >> 2, q = idx & 3;
        int sl = (q + 2 * (pp / 20)) % 5;
        uint4 v = *(const uint4*)(hb + (size_t)pp * 256 + ct * 32 + q * 8);
        *(uint4*)&img[im][pp * 40 + sl * 8] = v;
      }
    }
    __syncthreads();

    const short8* ap = A2 + ((size_t)wid * 648 + ct) * 256 + l15 * 4 + quad;

    short8 aF[2][4], bF[2][6];
    #pragma unroll
    for (int fo = 0; fo < 4; fo++) aF[0][fo] = ap[fo * 64];
    #pragma unroll
    for (int fn = 0; fn < 6; fn++){
      int f3 = (fn < 3) ? fn : fn - 3;
      const short8* ib = (fn < 3) ? i0p : i1p;
      bF[0][fn] = ib[bn[f3] * 5 + slc[f3]];
    }

    int rn = 0, sn = 0, r2m = 0;
    #pragma unroll 2
    for (int rs = 0; rs < 81; rs++){
      int cur = rs & 1, nxt = cur ^ 1;
      sn++;
      if (sn == 9){ sn = 0; rn++; r2m += 2; if (r2m >= 5) r2m -= 5; }
      int nrs = (rs < 80) ? rs + 1 : 80;
      int roff = rn * 20 + sn;
      const short8* apn = ap + (size_t)nrs * 2048;
      #pragma unroll
      for (int fo = 0; fo < 4; fo++) aF[nxt][fo] = apn[fo * 64];
      #pragma unroll
      for (int fn = 0; fn < 6; fn++){
        int f3 = (fn < 3) ? fn : fn - 3;
        const short8* ib = (fn < 3) ? i0p : i1p;
        int sl = slc[f3] + r2m; if (sl >= 5) sl -= 5;
        bF[nxt][fn] = ib[(bn[f3] + roff) * 5 + sl];
      }
      #pragma unroll
      for (int fo = 0; fo < 4; fo++)
        #pragma unroll
        for (int fn = 0; fn < 6; fn++)
          acc[fo][fn] = __builtin_amdgcn_mfma_f32_16x16x32_bf16(aF[cur][fo], bF[cur][fn], acc[fo][fn], 0, 0, 0);
    }
  }

  #pragma unroll
  for (int fn = 0; fn < 6; fn++){
    int im = (fn < 3) ? 0 : 1;
    int f3 = (fn < 3) ? fn : fn - 3;
    int pos = f3 * 16 + l15;
    if (pos < 36){
      float* cb = caps4 + ((size_t)kq * 256 + b0 + im) * 9216;
      #pragma unroll
      for (int fo = 0; fo < 4; fo++){
        int ob = wid * 64 + fo * 16 + quad * 4;
        #pragma unroll
        for (int rr = 0; rr < 4; rr++)
          cb[(size_t)(ob + rr) * 36 + pos] = acc[fo][fn][rr];
      }
    }
  }
}

// sum 4 kq-partials + bias, squash -> caps [b][i][8] fp32
__global__ __launch_bounds__(256) void squash4_kernel(const float* __restrict__ caps4,
    const float* __restrict__ bias, float* __restrict__ caps){
  size_t cid = (size_t)blockIdx.x * 256 + threadIdx.x;
  size_t base = cid * 8;
  const size_t STR = 2359296;
  float4 a0 = *(const float4*)(caps4 + base);
  float4 a1 = *(const float4*)(caps4 + base + 4);
  #pragma unroll
  for (int k = 1; k < 4; k++){
    float4 q0 = *(const float4*)(caps4 + k * STR + base);
    float4 q1 = *(const float4*)(caps4 + k * STR + base + 4);
    a0.x+=q0.x; a0.y+=q0.y; a0.z+=q0.z; a0.w+=q0.w;
    a1.x+=q1.x; a1.y+=q1.y; a1.z+=q1.z; a1.w+=q1.w;
  }
  int off = (int)(base % 9216);
  float v[8] = {a0.x,a0.y,a0.z,a0.w,a1.x,a1.y,a1.z,a1.w};
  #pragma unroll
  for (int e = 0; e < 8; e++) v[e] += bias[(off + e) / 36];
  float msq = 0.f;
  #pragma unroll
  for (int e = 0; e < 8; e++) msq += v[e]*v[e];
  float scale = sqrtf(msq) / (1.f + msq);
  float* cp = caps + base;
  #pragma unroll
  for (int e = 0; e < 8; e++) cp[e] = v[e]*scale;
}

// uT[b][jd][i] = sum_k Wrb[jd*8+k][i] * caps[b][i][k]  (bf16 out)
// grid (18 i-chunks, 64 = 16 b-groups x 4 jd-quarters), 2D (graph-replay
// safety: gridDim.z>1 diverged under the harness's graph timing in R9).
__global__ __launch_bounds__(256) void uhat_t_kernel(const float* __restrict__ caps,
    const ushort* __restrict__ Wrb, ushort* __restrict__ uT){
  __shared__ float cl[8 * 16 * 64];   // [k][bb][il], 32 KB
  int i0  = blockIdx.x * 64;
  int by  = blockIdx.y;
  int b0  = (by >> 2) * 16;
  int jd0 = (by & 3) * 40;
  int t = threadIdx.x, lane = t & 63, w = t >> 6;
  for (int f = t; f < 2048; f += 256){
    int base = f * 4; int bb = base >> 9; int r = base & 511;
    int il = r >> 3; int k = r & 7;
    float4 v = *(const float4*)(caps + ((size_t)(b0+bb)*1152 + i0 + il)*8 + k);
    cl[((k+0)*16+bb)*64+il] = v.x;
    cl[((k+1)*16+bb)*64+il] = v.y;
    cl[((k+2)*16+bb)*64+il] = v.z;
    cl[((k+3)*16+bb)*64+il] = v.w;
  }
  __syncthreads();
  for (int jj = 0; jj < 10; jj++){
    int jd = jd0 + w * 10 + jj;
    float wk[8];
    #pragma unroll
    for (int k = 0; k < 8; k++)
      wk[k] = bfu(Wrb[((size_t)jd * 8 + k) * 1152 + i0 + lane]);
    #pragma unroll
    for (int bb = 0; bb < 16; bb++){
      float acc = 0.f;
      #pragma unroll
      for (int k = 0; k < 8; k++) acc = fmaf(wk[k], cl[(k*16+bb)*64+lane], acc);
      __hip_bfloat16 hv = __float2bfloat16(acc);
      uT[((size_t)(b0+bb)*160 + jd)*1152 + i0 + lane] = *(ushort*)&hv;
    }
  }
}

// routing iteration: phase A (dots -> b -> softmax -> c, thread->i) +
// phase B (wave->jd, lanes->2i via uint loads). grid (3 chunks, 256 b).
// mode 0: c uniform 0.1 (phase B only); 1: b=d (write); 2: b+=d (read).
__global__ __launch_bounds__(384) void routeAB_kernel(
    const ushort* __restrict__ uT, const float* __restrict__ vin,
    float* __restrict__ bbuf, float* __restrict__ spart, int mode){
  __shared__ float c_l[384 * 11];
  __shared__ float vs[160];
  int ic = blockIdx.x;   // 0..2
  int b  = blockIdx.y;   // 0..255
  int t = threadIdx.x;
  int lane = t & 63, w = t >> 6;   // 6 waves
  const ushort* ub = uT + (size_t)b * 184320 + ic * 384;

  if (mode){
    if (t < 160) vs[t] = vin[b * 160 + t];
    __syncthreads();
    const ushort* up = ub + t;
    float d[10];
    #pragma unroll
    for (int j = 0; j < 10; j++){
      float dj = 0.f;
      #pragma unroll
      for (int dd = 0; dd < 16; dd++){
        int jd = j * 16 + dd;
        dj = fmaf(bfu(up[(size_t)jd * 1152]), vs[jd], dj);
      }
      d[j] = dj;
    }
    float* bp = bbuf + ((size_t)b * 1152 + ic * 384 + t) * 10;
    if (mode == 2){
      #pragma unroll
      for (int j = 0; j < 10; j++) d[j] += bp[j];
    } else {
      #pragma unroll
      for (int j = 0; j < 10; j++) bp[j] = d[j];
    }
    float m = d[0];
    #pragma unroll
    for (int j = 1; j < 10; j++) m = fmaxf(m, d[j]);
    float se = 0.f;
    #pragma unroll
    for (int j = 0; j < 10; j++){ d[j] = __expf(d[j] - m); se += d[j]; }
    float inv = 1.f / se;
    #pragma unroll
    for (int j = 0; j < 10; j++) c_l[t * 11 + j] = d[j] * inv;
  }
  __syncthreads();

  for (int jd = w; jd < 160; jd += 6){
    const uint* urow32 = (const uint*)(ub + (size_t)jd * 1152);
    float sacc = 0.f;
    if (mode){
      int jj = jd >> 4;
      #pragma unroll
      for (int st = 0; st < 3; st++){
        uint uv = urow32[st * 64 + lane];
        int i_l = (st * 64 + lane) * 2;
        sacc = fmaf(bfu((ushort)(uv & 0xffffu)), c_l[i_l * 11 + jj], sacc);
        sacc = fmaf(bfu((ushort)(uv >> 16)),     c_l[(i_l + 1) * 11 + jj], sacc);
      }
    } else {
      #pragma unroll
      for (int st = 0; st < 3; st++){
        uint uv = urow32[st * 64 + lane];
        sacc += bfu((ushort)(uv & 0xffffu)) + bfu((ushort)(uv >> 16));
      }
    }
    sacc += __shfl_xor(sacc, 32);
    sacc += __shfl_xor(sacc, 16);
    sacc += __shfl_xor(sacc, 8);
    sacc += __shfl_xor(sacc, 4);
    sacc += __shfl_xor(sacc, 2);
    sacc += __shfl_xor(sacc, 1);
    if (lane == 0) spart[((size_t)ic * 256 + b) * 160 + jd] = mode ? sacc : sacc * 0.1f;
  }
}

// sum 3 chunk partials + bias, squash over 16-groups -> v (or final out)
__global__ __launch_bounds__(160) void vsq_kernel(const float* __restrict__ spart,
    const float* __restrict__ dcb, float* __restrict__ vout){
  int b = blockIdx.x;
  int t = threadIdx.x;   // 0..159
  float s = dcb[t];
  #pragma unroll
  for (int ic = 0; ic < 3; ic++) s += spart[((size_t)ic * 256 + b) * 160 + t];
  float msq = s * s;
  msq += __shfl_xor(msq, 1, 16);
  msq += __shfl_xor(msq, 2, 16);
  msq += __shfl_xor(msq, 4, 16);
  msq += __shfl_xor(msq, 8, 16);
  float scale = sqrtf(msq) / (1.f + msq);
  vout[b * 160 + t] = s * scale;
}

extern "C" void kernel_launch(void* const* d_in, const int* in_sizes, int n_in,
                              void* d_out, int out_size, void* d_ws, size_t ws_size,
                              hipStream_t stream){
  (void)in_sizes; (void)n_in; (void)out_size; (void)ws_size;
  const float* x   = (const float*)d_in[0];
  const float* w1  = (const float*)d_in[1];
  const float* b1  = (const float*)d_in[2];
  const float* w2  = (const float*)d_in[3];
  const float* b2  = (const float*)d_in[4];
  const float* W   = (const float*)d_in[5];
  const float* dcb = (const float*)d_in[6];
  float* out = (float*)d_out;

  char* ws = (char*)d_ws;
  __hip_bfloat16* ht = (__hip_bfloat16*)(ws);
  ushort* A2s  = (ushort*)(ws + 52428800);
  float* caps4 = (float*)(ws + 63045632);
  ushort* uT   = (ushort*)(ws);                  // overlays ht/A2/caps4 (dead)
  float* caps  = (float*)(ws + 100794368);
  ushort* Wrb  = (ushort*)(ws + 110231552);
  float* bbuf  = (float*)(ws + 113180672);
  float* spart = (float*)(ws + 124977152);
  float* vbuf  = (float*)(ws + 125468672);

  conv1_kernel<<<dim3(256, 8), 640, 0, stream>>>(x, w1, b1, ht);
  arepack_kernel<<<256, 256, 0, stream>>>(w2, A2s);
  wrepack_kernel<<<dim3(18, 20), 256, 0, stream>>>(W, Wrb);
  conv2_mfma_kernel<<<512, 256, 0, stream>>>(ht, (const short8*)A2s, caps4);
  squash4_kernel<<<1152, 256, 0, stream>>>(caps4, b2, caps);
  uhat_t_kernel<<<dim3(18, 64), 256, 0, stream>>>(caps, Wrb, uT);
  routeAB_kernel<<<dim3(3, 256), 384, 0, stream>>>(uT, vbuf, bbuf, spart, 0);
  vsq_kernel<<<256, 160, 0, stream>>>(spart, dcb, vbuf);
  routeAB_kernel<<<dim3(3, 256), 384, 0, stream>>>(uT, vbuf, bbuf, spart, 1);
  vsq_kernel<<<256, 160, 0, stream>>>(spart, dcb, vbuf);
  routeAB_kernel<<<dim3(3, 256), 384, 0, stream>>>(uT, vbuf, bbuf, spart, 2);
  vsq_kernel<<<256, 160, 0, stream>>>(spart, dcb, out);
}